// Round 4
// baseline (1457.927 us; speedup 1.0000x reference)
//
#include <hip/hip_runtime.h>
#include <stdint.h>

#define Bn 8192
#define Dn 1024
#define Hn 4096
#define On 1024
#define En 8
#define Sn 2

typedef __attribute__((ext_vector_type(8))) short short8;
typedef __attribute__((ext_vector_type(4))) float f32x4;
typedef __attribute__((ext_vector_type(16))) float f32x16;

__device__ __forceinline__ unsigned short f2bf(float f) {
  unsigned int u = __float_as_uint(f);
  u += 0x7fff + ((u >> 16) & 1);   // round-to-nearest-even
  return (unsigned short)(u >> 16);
}

__device__ __forceinline__ void gload16(const void* g, void* l) {
  __builtin_amdgcn_global_load_lds(
      (const __attribute__((address_space(1))) unsigned int*)g,
      (__attribute__((address_space(3))) unsigned int*)l, 16, 0, 0);
}

// ---------------- gate (+ fused x->bf16 convert), NO ATOMICS ----------------
__global__ __launch_bounds__(256) void gate_k(
    const float* __restrict__ x, const float* __restrict__ Wg,
    const float* __restrict__ bg, unsigned short* __restrict__ xb,
    float* __restrict__ rw, int* __restrict__ ri) {
  {
    size_t base = (size_t)blockIdx.x * 1024;
    const float4* xi = (const float4*)x + base;
    ushort4* xo = (ushort4*)xb + base;
#pragma unroll
    for (int k2 = 0; k2 < 4; k2++) {
      float4 v = xi[k2 * 256 + threadIdx.x];
      ushort4 o;
      o.x = f2bf(v.x); o.y = f2bf(v.y); o.z = f2bf(v.z); o.w = f2bf(v.w);
      xo[k2 * 256 + threadIdx.x] = o;
    }
  }
  __shared__ __align__(16) float wgs[Dn * 10];
  for (int i = threadIdx.x; i < 2560; i += 256)
    ((float4*)wgs)[i] = ((const float4*)Wg)[i];
  __syncthreads();
  int lane = threadIdx.x & 63, wave = threadIdx.x >> 6;
  int r = blockIdx.x * 4 + wave;
  const float* xr = x + (size_t)r * Dn;
  float p[10];
#pragma unroll
  for (int j = 0; j < 10; j++) p[j] = 0.f;
  for (int d = lane; d < Dn; d += 64) {
    float xv = xr[d];
#pragma unroll
    for (int j = 0; j < 10; j++) p[j] += xv * wgs[d * 10 + j];
  }
#pragma unroll
  for (int off = 32; off; off >>= 1)
#pragma unroll
    for (int j = 0; j < 10; j++) p[j] += __shfl_xor(p[j], off);
  float mx = -1e30f;
#pragma unroll
  for (int j = 0; j < 10; j++) { p[j] += bg[j]; mx = fmaxf(mx, p[j]); }
  float s = 0.f;
#pragma unroll
  for (int j = 0; j < 10; j++) { p[j] = expf(p[j] - mx); s += p[j]; }
  float inv = 1.f / s;
  int i0 = 2, i1 = 2; float v0 = -1e30f, v1 = -1e30f;
#pragma unroll
  for (int j = 2; j < 10; j++) {
    float v = p[j];
    if (v > v0) { v1 = v0; i1 = i0; v0 = v; i0 = j; }
    else if (v > v1) { v1 = v; i1 = j; }
  }
  if (lane == 0) {
    rw[r * 4 + 0] = v0 * inv;
    rw[r * 4 + 1] = v1 * inv;
    rw[r * 4 + 2] = p[0] * inv;
    rw[r * 4 + 3] = p[1] * inv;
    ri[r * 2 + 0] = i0 - 2;
    ri[r * 2 + 1] = i1 - 2;
  }
}

// ---------------- count: 16 blocks, register histograms, 128 atomics total ----------------
__global__ __launch_bounds__(256) void count_k(const int* __restrict__ ri,
                                               int* __restrict__ cnt) {
  int c[8];
#pragma unroll
  for (int j = 0; j < 8; j++) c[j] = 0;
  int base = blockIdx.x * 1024;
  for (int i = threadIdx.x; i < 1024; i += 256) {
    int e = ri[base + i];
#pragma unroll
    for (int j = 0; j < 8; j++) c[j] += (e == j) ? 1 : 0;
  }
#pragma unroll
  for (int j = 0; j < 8; j++)
#pragma unroll
    for (int off = 32; off; off >>= 1) c[j] += __shfl_xor(c[j], off);
  __shared__ int sc[4][8];
  int wv = threadIdx.x >> 6, lane = threadIdx.x & 63;
  if (lane == 0)
#pragma unroll
    for (int j = 0; j < 8; j++) sc[wv][j] = c[j];
  __syncthreads();
  if (threadIdx.x < 8)
    atomicAdd(&cnt[threadIdx.x], sc[0][threadIdx.x] + sc[1][threadIdx.x] +
                                 sc[2][threadIdx.x] + sc[3][threadIdx.x]);
}

// ---------------- weight transposes -> CHUNK-MAJOR layout ----------------
// out[e][nt = n/256][c = k/8][r = n%256][8]  (bf16)
__global__ __launch_bounds__(256) void tcvt_all(
    const float* __restrict__ W1, const float* __restrict__ W2,
    const float* __restrict__ Ws1, const float* __restrict__ Ws2,
    unsigned short* __restrict__ w1t, unsigned short* __restrict__ w2t,
    unsigned short* __restrict__ ws1t, unsigned short* __restrict__ ws2t) {
  __shared__ float t[128][65];
  int bid = blockIdx.x;
  int u = bid >> 9, r = bid & 511;   // 512 tiles per unit
  const float* in; unsigned short* out; int Kd, Nd;
  if (u < 8)       { Kd = Dn; Nd = Hn; in = W1  + (size_t)u * Dn * Hn;        out = w1t  + (size_t)u * Dn * Hn; }
  else if (u < 16) { Kd = Hn; Nd = On; in = W2  + (size_t)(u - 8) * Hn * On;  out = w2t  + (size_t)(u - 8) * Hn * On; }
  else if (u < 18) { Kd = Dn; Nd = Hn; in = Ws1 + (size_t)(u - 16) * Dn * Hn; out = ws1t + (size_t)(u - 16) * Dn * Hn; }
  else             { Kd = Hn; Nd = On; in = Ws2 + (size_t)(u - 18) * Hn * On; out = ws2t + (size_t)(u - 18) * Hn * On; }
  int by, bx;
  if (Kd == Dn) { by = (r & 7) * 128;  bx = (r >> 3) * 64; }
  else          { by = (r & 31) * 128; bx = (r >> 5) * 64; }
  int tid = threadIdx.x;
#pragma unroll
  for (int q = 0; q < 8; q++) {
    int idx = q * 256 + tid;
    int k = idx >> 4, f4 = (idx & 15) * 4;
    float4 v = *(const float4*)&in[(size_t)(by + k) * Nd + bx + f4];
    t[k][f4] = v.x; t[k][f4 + 1] = v.y; t[k][f4 + 2] = v.z; t[k][f4 + 3] = v.w;
  }
  __syncthreads();
  int KC = Kd >> 3;
#pragma unroll
  for (int p = 0; p < 4; p++) {
    int idx = p * 256 + tid;
    int nl = idx & 63, kgi = idx >> 6;
    int kg = kgi * 8;
    int ng = bx + nl;
    short8 v;
#pragma unroll
    for (int j = 0; j < 8; j++) v[j] = (short)f2bf(t[kg + j][nl]);
    size_t o = ((((size_t)(ng >> 8) * KC + (by >> 3) + kgi) * 256 + (ng & 255)) << 3);
    *(short8*)&out[o] = v;
  }
}

// ---------------- build: LDS ranks + 8 global atomics/block ----------------
__global__ __launch_bounds__(256) void build_k(
    const float* __restrict__ rw, const int* __restrict__ ri,
    const int* __restrict__ cnt, int* __restrict__ cnt2,
    int* __restrict__ slot_row, float* __restrict__ slot_w,
    int* __restrict__ slot_dst) {
  __shared__ int lcnt[8], lbase[8];
  int tid = threadIdx.x;
  if (tid < 8) lcnt[tid] = 0;
  __syncthreads();
  int r = blockIdx.x * 256 + tid;
  int e0 = ri[r * 2 + 0], e1 = ri[r * 2 + 1];
  int rk0 = atomicAdd(&lcnt[e0], 1);
  int rk1 = atomicAdd(&lcnt[e1], 1);
  __syncthreads();
  if (tid < 8) lbase[tid] = atomicAdd(&cnt2[tid], lcnt[tid]);
  __syncthreads();
  int off0 = 0, off1 = 0;
#pragma unroll
  for (int i = 0; i < 8; i++) {
    int ci = cnt[i];
    off0 += (i < e0) ? ci : 0;
    off1 += (i < e1) ? ci : 0;
  }
  int s0 = off0 + lbase[e0] + rk0;
  int s1 = off1 + lbase[e1] + rk1;
  slot_row[s0] = r; slot_w[s0] = rw[r * 4 + 0]; slot_dst[s0] = r * 4 + 0;
  slot_row[s1] = r; slot_w[s1] = rw[r * 4 + 1]; slot_dst[s1] = r * 4 + 1;
#pragma unroll
  for (int s = 0; s < 2; s++) {
    int slot = 16384 + s * Bn + r;
    slot_row[slot] = r;
    slot_w[slot] = rw[r * 4 + 2 + s];
    slot_dst[slot] = r * 4 + 2 + s;
  }
}

// ==== 128x256 BK=32 8-wave GEMM: 32x32 MFMA, hybrid LDS ====
// A: row-major LDS [128][4 chunks][8] w/ XOR swizzle chunk=c^((l31>>1)&3)
// B: chunk-major LDS [4c][256][8] staged from CHUNK-MAJOR GLOBAL (tcvt_all)
// R22: 2-slot double buffer (48KB LDS -> 3 blocks/CU; was 3-slot 72KB ->
// 2 blocks/CU).  m132 cliff: this structure needs the 3rd co-resident block
// to overlap barrier drains.  Counted hand-off vmcnt(3): tile t's 3 loads
// complete, tile t+1's stay in flight (never drain to 0).
// Epilogue: Y stores + final_k (R0 proven; atomics measured +24us, rejected).
// C/D layout (m74/m101): col=lane&31, row=(reg&3)+8*(reg>>2)+4*(lane>>5).

__global__ __launch_bounds__(512, 6) void gemm1_u(
    const unsigned short* __restrict__ xb,
    const unsigned short* __restrict__ w1c, const unsigned short* __restrict__ ws1c,
    const float* __restrict__ b1, const float* __restrict__ bs1,
    const int* __restrict__ cnt, const int* __restrict__ slotRow,
    unsigned short* __restrict__ h, int ubase, int hsh) {
  int total = gridDim.x;
  int gid = blockIdx.x;
  int swz = (gid & 7) * (total >> 3) + (gid >> 3);
  int u = ubase + (swz >> 10);          // per_e = 16*64 = 1024
  int rem = swz & 1023;
  int mt = rem & 63;
  int nt = rem >> 6;

  int M, off, hoff;
  const unsigned short* Bte; const float* be;
  if (u < 8) {
    M = cnt[u]; off = 0;
    for (int i = 0; i < u; i++) off += cnt[i];
    hoff = off;
    Bte = w1c + (size_t)u * Hn * Dn; be = b1 + (size_t)u * Hn;
  } else {
    int s = u - 8;
    M = Bn; off = 16384 + s * Bn; hoff = hsh + s * Bn;
    Bte = ws1c + (size_t)s * Hn * Dn; be = bs1 + (size_t)s * Hn;
  }
  int mbase = mt * 128;
  if (mbase >= M) return;
  int n0 = nt * 256;

  __shared__ __align__(16) unsigned short shb[24576];

  int tid = threadIdx.x;
  int lane = tid & 63, wv = tid >> 6;
  int wm = wv >> 2, wn = wv & 3;
  int l31 = lane & 31, l5 = lane >> 5;
  int rswA = (l31 >> 1) & 3;

  int scol = (((tid & 3) ^ ((tid >> 3) & 3)) * 8);
  int mi = mbase + (tid >> 2);
  if (mi > M - 1) mi = M - 1;
  int grow = slotRow[off + mi];
  const unsigned short* agp = xb + (size_t)grow * Dn + scol;
  const unsigned short* Bnt = Bte + (size_t)nt * 262144;   // 128*256*8
  const unsigned short* bgp0 = Bnt + (((size_t)(tid >> 8) * 256 + (tid & 255)) << 3);
  const unsigned short* bgp1 = bgp0 + 4096;                // chunks +2

  f32x16 acc[2][2];
#pragma unroll
  for (int i = 0; i < 2; i++)
#pragma unroll
    for (int j = 0; j < 2; j++)
#pragma unroll
      for (int q = 0; q < 16; q++) acc[i][j][q] = 0.f;

  auto STAGE = [&](int slot, int tt) {
    int so = slot * 12288;
    gload16(agp + tt * 32, &shb[so + wv * 512]);
    gload16(bgp0 + tt * 8192, &shb[so + 4096 + wv * 512]);
    gload16(bgp1 + tt * 8192, &shb[so + 8192 + wv * 512]);
  };
  auto COMPUTE = [&](int slot) {
    int so = slot * 12288;
#pragma unroll
    for (int kk = 0; kk < 2; kk++) {
      int cA = (((kk * 2 + l5) ^ rswA) * 8);
      short8 a0 = *(const short8*)&shb[so + (wm * 64 + l31) * 32 + cA];
      short8 a1 = *(const short8*)&shb[so + (wm * 64 + 32 + l31) * 32 + cA];
      int cB = (kk * 2 + l5) * 256;
      short8 b0 = *(const short8*)&shb[so + 4096 + (cB + wn * 64 + l31) * 8];
      short8 b1 = *(const short8*)&shb[so + 4096 + (cB + wn * 64 + 32 + l31) * 8];
      acc[0][0] = __builtin_amdgcn_mfma_f32_32x32x16_bf16(a0, b0, acc[0][0], 0, 0, 0);
      acc[0][1] = __builtin_amdgcn_mfma_f32_32x32x16_bf16(a0, b1, acc[0][1], 0, 0, 0);
      acc[1][0] = __builtin_amdgcn_mfma_f32_32x32x16_bf16(a1, b0, acc[1][0], 0, 0, 0);
      acc[1][1] = __builtin_amdgcn_mfma_f32_32x32x16_bf16(a1, b1, acc[1][1], 0, 0, 0);
    }
  };

  const int NT = Dn >> 5;   // 32
  STAGE(0, 0);
  int cur = 0;
  for (int t = 0; t < NT; ++t) {
    int tn = (t + 1 < NT) ? (t + 1) : (NT - 1);
    STAGE(cur ^ 1, tn);
    asm volatile("s_waitcnt vmcnt(3)" ::: "memory");
    asm volatile("s_barrier" ::: "memory");
    COMPUTE(cur);
    asm volatile("s_barrier" ::: "memory");
    cur ^= 1;
  }

  float bev[2];
#pragma unroll
  for (int g = 0; g < 2; g++) bev[g] = be[n0 + wn * 64 + g * 32 + l31];
#pragma unroll
  for (int i = 0; i < 2; i++) {
#pragma unroll
    for (int reg = 0; reg < 16; reg++) {
      int rr = (reg & 3) + 8 * (reg >> 2) + 4 * l5;
      int m = mbase + wm * 64 + i * 32 + rr;
      if (m < M) {
        size_t hrow = (size_t)(hoff + m) * Hn;
#pragma unroll
        for (int g = 0; g < 2; g++) {
          int n = n0 + wn * 64 + g * 32 + l31;
          float v = acc[i][g][reg] + bev[g];
          h[hrow + n] = f2bf(fmaxf(v, 0.f));
        }
      }
    }
  }
}

__global__ __launch_bounds__(512, 6) void gemm2_u(
    const unsigned short* __restrict__ hin,
    const unsigned short* __restrict__ w2c, const unsigned short* __restrict__ ws2c,
    const float* __restrict__ b2, const float* __restrict__ bs2,
    const int* __restrict__ cnt, const float* __restrict__ slotW,
    const int* __restrict__ slotDst, float* __restrict__ Y, int ubase, int hsh) {
  int total = gridDim.x;
  int gid = blockIdx.x;
  int swz = (gid & 7) * (total >> 3) + (gid >> 3);
  int u = ubase + (swz >> 8);           // per_e = 4*64 = 256
  int rem = swz & 255;
  int mt = rem & 63;
  int nt = rem >> 6;

  int M, off, hoff;
  const unsigned short* Bte; const float* be;
  if (u < 8) {
    M = cnt[u]; off = 0;
    for (int i = 0; i < u; i++) off += cnt[i];
    hoff = off;
    Bte = w2c + (size_t)u * On * Hn; be = b2 + (size_t)u * On;
  } else {
    int s = u - 8;
    M = Bn; off = 16384 + s * Bn; hoff = hsh + s * Bn;
    Bte = ws2c + (size_t)s * On * Hn; be = bs2 + (size_t)s * On;
  }
  int mbase = mt * 128;
  if (mbase >= M) return;
  int n0 = nt * 256;

  __shared__ __align__(16) unsigned short shb[24576];

  int tid = threadIdx.x;
  int lane = tid & 63, wv = tid >> 6;
  int wm = wv >> 2, wn = wv & 3;
  int l31 = lane & 31, l5 = lane >> 5;
  int rswA = (l31 >> 1) & 3;

  int scol = (((tid & 3) ^ ((tid >> 3) & 3)) * 8);
  int mi = mbase + (tid >> 2);
  if (mi > M - 1) mi = M - 1;
  const unsigned short* agp = hin + (size_t)(hoff + mi) * Hn + scol;
  const unsigned short* Bnt = Bte + (size_t)nt * 1048576;   // 512*256*8
  const unsigned short* bgp0 = Bnt + (((size_t)(tid >> 8) * 256 + (tid & 255)) << 3);
  const unsigned short* bgp1 = bgp0 + 4096;

  f32x16 acc[2][2];
#pragma unroll
  for (int i = 0; i < 2; i++)
#pragma unroll
    for (int j = 0; j < 2; j++)
#pragma unroll
      for (int q = 0; q < 16; q++) acc[i][j][q] = 0.f;

  auto STAGE = [&](int slot, int tt) {
    int so = slot * 12288;
    gload16(agp + tt * 32, &shb[so + wv * 512]);
    gload16(bgp0 + tt * 8192, &shb[so + 4096 + wv * 512]);
    gload16(bgp1 + tt * 8192, &shb[so + 8192 + wv * 512]);
  };
  auto COMPUTE = [&](int slot) {
    int so = slot * 12288;
#pragma unroll
    for (int kk = 0; kk < 2; kk++) {
      int cA = (((kk * 2 + l5) ^ rswA) * 8);
      short8 a0 = *(const short8*)&shb[so + (wm * 64 + l31) * 32 + cA];
      short8 a1 = *(const short8*)&shb[so + (wm * 64 + 32 + l31) * 32 + cA];
      int cB = (kk * 2 + l5) * 256;
      short8 b0 = *(const short8*)&shb[so + 4096 + (cB + wn * 64 + l31) * 8];
      short8 b1 = *(const short8*)&shb[so + 4096 + (cB + wn * 64 + 32 + l31) * 8];
      acc[0][0] = __builtin_amdgcn_mfma_f32_32x32x16_bf16(a0, b0, acc[0][0], 0, 0, 0);
      acc[0][1] = __builtin_amdgcn_mfma_f32_32x32x16_bf16(a0, b1, acc[0][1], 0, 0, 0);
      acc[1][0] = __builtin_amdgcn_mfma_f32_32x32x16_bf16(a1, b0, acc[1][0], 0, 0, 0);
      acc[1][1] = __builtin_amdgcn_mfma_f32_32x32x16_bf16(a1, b1, acc[1][1], 0, 0, 0);
    }
  };

  const int NT = Hn >> 5;   // 128
  STAGE(0, 0);
  int cur = 0;
  for (int t = 0; t < NT; ++t) {
    int tn = (t + 1 < NT) ? (t + 1) : (NT - 1);
    STAGE(cur ^ 1, tn);
    asm volatile("s_waitcnt vmcnt(3)" ::: "memory");
    asm volatile("s_barrier" ::: "memory");
    COMPUTE(cur);
    asm volatile("s_barrier" ::: "memory");
    cur ^= 1;
  }

  float bev[2];
#pragma unroll
  for (int g = 0; g < 2; g++) bev[g] = be[n0 + wn * 64 + g * 32 + l31];
#pragma unroll
  for (int i = 0; i < 2; i++) {
#pragma unroll
    for (int reg = 0; reg < 16; reg++) {
      int rr = (reg & 3) + 8 * (reg >> 2) + 4 * l5;
      int m = mbase + wm * 64 + i * 32 + rr;
      if (m < M) {
        float wgt = slotW[off + m];
        size_t yrow = (size_t)slotDst[off + m] * On;
#pragma unroll
        for (int g = 0; g < 2; g++) {
          int n = n0 + wn * 64 + g * 32 + l31;
          Y[yrow + n] = wgt * (acc[i][g][reg] + bev[g]);
        }
      }
    }
  }
}

__global__ void final_k(const float* __restrict__ Y, float* __restrict__ out) {
  int i = blockIdx.x * 256 + threadIdx.x;   // float4 index over Bn*On/4, exact
  int b = i >> 8;
  int c = i & 255;
  const float4* y = (const float4*)Y;
  float4 a0 = y[((size_t)b * 4 + 0) * 256 + c];
  float4 a1 = y[((size_t)b * 4 + 1) * 256 + c];
  float4 a2 = y[((size_t)b * 4 + 2) * 256 + c];
  float4 a3 = y[((size_t)b * 4 + 3) * 256 + c];
  float4 o;
  o.x = a0.x + a1.x + a2.x + a3.x;
  o.y = a0.y + a1.y + a2.y + a3.y;
  o.z = a0.z + a1.z + a2.z + a3.z;
  o.w = a0.w + a1.w + a2.w + a3.w;
  ((float4*)out)[i] = o;
}

extern "C" void kernel_launch(void* const* d_in, const int* in_sizes, int n_in,
                              void* d_out, int out_size, void* d_ws, size_t ws_size,
                              hipStream_t stream) {
  const float* x   = (const float*)d_in[0];
  const float* W1  = (const float*)d_in[1];
  const float* b1  = (const float*)d_in[2];
  const float* W2  = (const float*)d_in[3];
  const float* b2  = (const float*)d_in[4];
  const float* Ws1 = (const float*)d_in[5];
  const float* bs1 = (const float*)d_in[6];
  const float* Ws2 = (const float*)d_in[7];
  const float* bs2 = (const float*)d_in[8];
  const float* Wg  = (const float*)d_in[9];
  const float* bg  = (const float*)d_in[10];
  float* out = (float*)d_out;

  // FALLBACK-ONLY workspace plan (hbuf = 16384 rows, reused expert->shared).
  char* w = (char*)d_ws;
  size_t p = 0;
  auto alloc = [&](size_t n) { char* r = w + p; p = (p + n + 255) & ~(size_t)255; return r; };
  unsigned short* xb   = (unsigned short*)alloc((size_t)Bn * Dn * 2);
  unsigned short* w1t  = (unsigned short*)alloc((size_t)En * Hn * Dn * 2);
  unsigned short* w2t  = (unsigned short*)alloc((size_t)En * On * Hn * 2);
  unsigned short* ws1t = (unsigned short*)alloc((size_t)Sn * Hn * Dn * 2);
  unsigned short* ws2t = (unsigned short*)alloc((size_t)Sn * On * Hn * 2);
  unsigned short* hbuf = (unsigned short*)alloc((size_t)16384 * Hn * 2);
  float* Y             = (float*)alloc((size_t)Bn * 4 * On * 4);
  float* rw            = (float*)alloc((size_t)Bn * 4 * 4);
  int* ri              = (int*)alloc((size_t)Bn * 2 * 4);
  int* ctrl            = (int*)alloc(256);
  int* slot_row        = (int*)alloc((size_t)32768 * 4);
  float* slot_w        = (float*)alloc((size_t)32768 * 4);
  int* slot_dst        = (int*)alloc((size_t)32768 * 4);
  if (p > ws_size) return;   // ws too small

  int* cnt  = ctrl;
  int* cnt2 = ctrl + 8;

  hipMemsetAsync(ctrl, 0, 64, stream);
  gate_k<<<2048, 256, 0, stream>>>(x, Wg, bg, xb, rw, ri);
  tcvt_all<<<10240, 256, 0, stream>>>(W1, W2, Ws1, Ws2, w1t, w2t, ws1t, ws2t);
  count_k<<<16, 256, 0, stream>>>(ri, cnt);
  build_k<<<32, 256, 0, stream>>>(rw, ri, cnt, cnt2, slot_row, slot_w, slot_dst);

  // experts (u=0..7): hbuf rows 0..16383, then consumed by gemm2
  gemm1_u<<<8 * 1024, 512, 0, stream>>>(xb, w1t, ws1t, b1, bs1, cnt, slot_row,
                                        hbuf, 0, 0);
  gemm2_u<<<8 * 256, 512, 0, stream>>>(hbuf, w2t, ws2t, b2, bs2, cnt, slot_w,
                                       slot_dst, Y, 0, 0);
  // shared (u=8..9): hbuf rows reused
  gemm1_u<<<2 * 1024, 512, 0, stream>>>(xb, w1t, ws1t, b1, bs1, cnt, slot_row,
                                        hbuf, 8, 0);
  gemm2_u<<<2 * 256, 512, 0, stream>>>(hbuf, w2t, ws2t, b2, bs2, cnt, slot_w,
                                       slot_dst, Y, 8, 0);
  final_k<<<8192, 256, 0, stream>>>(Y, out);
}

// Round 5
// 859.644 us; speedup vs baseline: 1.6960x; 1.6960x over previous
//
#include <hip/hip_runtime.h>
#include <stdint.h>

#define Bn 8192
#define Dn 1024
#define Hn 4096
#define On 1024
#define En 8
#define Sn 2

typedef __attribute__((ext_vector_type(8))) short short8;
typedef __attribute__((ext_vector_type(4))) float f32x4;
typedef __attribute__((ext_vector_type(16))) float f32x16;

__device__ __forceinline__ unsigned short f2bf(float f) {
  unsigned int u = __float_as_uint(f);
  u += 0x7fff + ((u >> 16) & 1);   // round-to-nearest-even
  return (unsigned short)(u >> 16);
}

__device__ __forceinline__ void gload16(const void* g, void* l) {
  __builtin_amdgcn_global_load_lds(
      (const __attribute__((address_space(1))) unsigned int*)g,
      (__attribute__((address_space(3))) unsigned int*)l, 16, 0, 0);
}

// ---------------- gate (+ fused x->bf16 convert), NO ATOMICS ----------------
__global__ __launch_bounds__(256) void gate_k(
    const float* __restrict__ x, const float* __restrict__ Wg,
    const float* __restrict__ bg, unsigned short* __restrict__ xb,
    float* __restrict__ rw, int* __restrict__ ri) {
  {
    size_t base = (size_t)blockIdx.x * 1024;
    const float4* xi = (const float4*)x + base;
    ushort4* xo = (ushort4*)xb + base;
#pragma unroll
    for (int k2 = 0; k2 < 4; k2++) {
      float4 v = xi[k2 * 256 + threadIdx.x];
      ushort4 o;
      o.x = f2bf(v.x); o.y = f2bf(v.y); o.z = f2bf(v.z); o.w = f2bf(v.w);
      xo[k2 * 256 + threadIdx.x] = o;
    }
  }
  __shared__ __align__(16) float wgs[Dn * 10];
  for (int i = threadIdx.x; i < 2560; i += 256)
    ((float4*)wgs)[i] = ((const float4*)Wg)[i];
  __syncthreads();
  int lane = threadIdx.x & 63, wave = threadIdx.x >> 6;
  int r = blockIdx.x * 4 + wave;
  const float* xr = x + (size_t)r * Dn;
  float p[10];
#pragma unroll
  for (int j = 0; j < 10; j++) p[j] = 0.f;
  for (int d = lane; d < Dn; d += 64) {
    float xv = xr[d];
#pragma unroll
    for (int j = 0; j < 10; j++) p[j] += xv * wgs[d * 10 + j];
  }
#pragma unroll
  for (int off = 32; off; off >>= 1)
#pragma unroll
    for (int j = 0; j < 10; j++) p[j] += __shfl_xor(p[j], off);
  float mx = -1e30f;
#pragma unroll
  for (int j = 0; j < 10; j++) { p[j] += bg[j]; mx = fmaxf(mx, p[j]); }
  float s = 0.f;
#pragma unroll
  for (int j = 0; j < 10; j++) { p[j] = expf(p[j] - mx); s += p[j]; }
  float inv = 1.f / s;
  int i0 = 2, i1 = 2; float v0 = -1e30f, v1 = -1e30f;
#pragma unroll
  for (int j = 2; j < 10; j++) {
    float v = p[j];
    if (v > v0) { v1 = v0; i1 = i0; v0 = v; i0 = j; }
    else if (v > v1) { v1 = v; i1 = j; }
  }
  if (lane == 0) {
    rw[r * 4 + 0] = v0 * inv;
    rw[r * 4 + 1] = v1 * inv;
    rw[r * 4 + 2] = p[0] * inv;
    rw[r * 4 + 3] = p[1] * inv;
    ri[r * 2 + 0] = i0 - 2;
    ri[r * 2 + 1] = i1 - 2;
  }
}

// ---------------- count: 16 blocks, register histograms, 128 atomics total ----------------
__global__ __launch_bounds__(256) void count_k(const int* __restrict__ ri,
                                               int* __restrict__ cnt) {
  int c[8];
#pragma unroll
  for (int j = 0; j < 8; j++) c[j] = 0;
  int base = blockIdx.x * 1024;
  for (int i = threadIdx.x; i < 1024; i += 256) {
    int e = ri[base + i];
#pragma unroll
    for (int j = 0; j < 8; j++) c[j] += (e == j) ? 1 : 0;
  }
#pragma unroll
  for (int j = 0; j < 8; j++)
#pragma unroll
    for (int off = 32; off; off >>= 1) c[j] += __shfl_xor(c[j], off);
  __shared__ int sc[4][8];
  int wv = threadIdx.x >> 6, lane = threadIdx.x & 63;
  if (lane == 0)
#pragma unroll
    for (int j = 0; j < 8; j++) sc[wv][j] = c[j];
  __syncthreads();
  if (threadIdx.x < 8)
    atomicAdd(&cnt[threadIdx.x], sc[0][threadIdx.x] + sc[1][threadIdx.x] +
                                 sc[2][threadIdx.x] + sc[3][threadIdx.x]);
}

// ---------------- weight transposes -> CHUNK-MAJOR layout ----------------
// out[e][nt = n/256][c = k/8][r = n%256][8]  (bf16)
__global__ __launch_bounds__(256) void tcvt_all(
    const float* __restrict__ W1, const float* __restrict__ W2,
    const float* __restrict__ Ws1, const float* __restrict__ Ws2,
    unsigned short* __restrict__ w1t, unsigned short* __restrict__ w2t,
    unsigned short* __restrict__ ws1t, unsigned short* __restrict__ ws2t) {
  __shared__ float t[128][65];
  int bid = blockIdx.x;
  int u = bid >> 9, r = bid & 511;   // 512 tiles per unit
  const float* in; unsigned short* out; int Kd, Nd;
  if (u < 8)       { Kd = Dn; Nd = Hn; in = W1  + (size_t)u * Dn * Hn;        out = w1t  + (size_t)u * Dn * Hn; }
  else if (u < 16) { Kd = Hn; Nd = On; in = W2  + (size_t)(u - 8) * Hn * On;  out = w2t  + (size_t)(u - 8) * Hn * On; }
  else if (u < 18) { Kd = Dn; Nd = Hn; in = Ws1 + (size_t)(u - 16) * Dn * Hn; out = ws1t + (size_t)(u - 16) * Dn * Hn; }
  else             { Kd = Hn; Nd = On; in = Ws2 + (size_t)(u - 18) * Hn * On; out = ws2t + (size_t)(u - 18) * Hn * On; }
  int by, bx;
  if (Kd == Dn) { by = (r & 7) * 128;  bx = (r >> 3) * 64; }
  else          { by = (r & 31) * 128; bx = (r >> 5) * 64; }
  int tid = threadIdx.x;
#pragma unroll
  for (int q = 0; q < 8; q++) {
    int idx = q * 256 + tid;
    int k = idx >> 4, f4 = (idx & 15) * 4;
    float4 v = *(const float4*)&in[(size_t)(by + k) * Nd + bx + f4];
    t[k][f4] = v.x; t[k][f4 + 1] = v.y; t[k][f4 + 2] = v.z; t[k][f4 + 3] = v.w;
  }
  __syncthreads();
  int KC = Kd >> 3;
#pragma unroll
  for (int p = 0; p < 4; p++) {
    int idx = p * 256 + tid;
    int nl = idx & 63, kgi = idx >> 6;
    int kg = kgi * 8;
    int ng = bx + nl;
    short8 v;
#pragma unroll
    for (int j = 0; j < 8; j++) v[j] = (short)f2bf(t[kg + j][nl]);
    size_t o = ((((size_t)(ng >> 8) * KC + (by >> 3) + kgi) * 256 + (ng & 255)) << 3);
    *(short8*)&out[o] = v;
  }
}

// ---------------- build: LDS ranks + 8 global atomics/block ----------------
// expert slot_dst = r*2+s  (Y rows [0,16384));  shared handled by gemm2s_m.
__global__ __launch_bounds__(256) void build_k(
    const float* __restrict__ rw, const int* __restrict__ ri,
    const int* __restrict__ cnt, int* __restrict__ cnt2,
    int* __restrict__ slot_row, float* __restrict__ slot_w,
    int* __restrict__ slot_dst) {
  __shared__ int lcnt[8], lbase[8];
  int tid = threadIdx.x;
  if (tid < 8) lcnt[tid] = 0;
  __syncthreads();
  int r = blockIdx.x * 256 + tid;
  int e0 = ri[r * 2 + 0], e1 = ri[r * 2 + 1];
  int rk0 = atomicAdd(&lcnt[e0], 1);
  int rk1 = atomicAdd(&lcnt[e1], 1);
  __syncthreads();
  if (tid < 8) lbase[tid] = atomicAdd(&cnt2[tid], lcnt[tid]);
  __syncthreads();
  int off0 = 0, off1 = 0;
#pragma unroll
  for (int i = 0; i < 8; i++) {
    int ci = cnt[i];
    off0 += (i < e0) ? ci : 0;
    off1 += (i < e1) ? ci : 0;
  }
  int s0 = off0 + lbase[e0] + rk0;
  int s1 = off1 + lbase[e1] + rk1;
  slot_row[s0] = r; slot_w[s0] = rw[r * 4 + 0]; slot_dst[s0] = r * 2 + 0;
  slot_row[s1] = r; slot_w[s1] = rw[r * 4 + 1]; slot_dst[s1] = r * 2 + 1;
#pragma unroll
  for (int s = 0; s < 2; s++) {
    int slot = 16384 + s * Bn + r;
    slot_row[slot] = r;
    slot_w[slot] = rw[r * 4 + 2 + s];
    slot_dst[slot] = 0;   // unused
  }
}

// ==== 128x256 BK=32 8-wave GEMM: 32x32 MFMA, hybrid LDS (R0/R18 FROZEN) ====
// A: row-major LDS [128][4 chunks][8] w/ XOR swizzle chunk=c^((l31>>1)&3)
// B: chunk-major LDS [4c][256][8] staged from CHUNK-MAJOR GLOBAL (tcvt_all)
// Loop: STAGE(sC,t+2) -> vmcnt(6) -> s_barrier -> COMPUTE(sA) -> s_barrier.
// DO NOT TOUCH: depth-1 (R22) broke cohort lockstep -> FETCH 2.6x, 390us;
// phase-split (R19) serialized ds_read vs MFMA -> 725us; atomics (R21) +24us.
// C/D layout (m74/m101): col=lane&31, row=(reg&3)+8*(reg>>2)+4*(lane>>5).

__global__ __launch_bounds__(512, 4) void gemm1_u(
    const unsigned short* __restrict__ xb,
    const unsigned short* __restrict__ w1c, const unsigned short* __restrict__ ws1c,
    const float* __restrict__ b1, const float* __restrict__ bs1,
    const int* __restrict__ cnt, const int* __restrict__ slotRow,
    unsigned short* __restrict__ h, int ubase, int hsh) {
  int total = gridDim.x;
  int gid = blockIdx.x;
  int swz = (gid & 7) * (total >> 3) + (gid >> 3);
  int u = ubase + (swz >> 10);          // per_e = 16*64 = 1024
  int rem = swz & 1023;
  int mt = rem & 63;
  int nt = rem >> 6;

  int M, off, hoff;
  const unsigned short* Bte; const float* be;
  if (u < 8) {
    M = cnt[u]; off = 0;
    for (int i = 0; i < u; i++) off += cnt[i];
    hoff = off;
    Bte = w1c + (size_t)u * Hn * Dn; be = b1 + (size_t)u * Hn;
  } else {
    int s = u - 8;
    M = Bn; off = 16384 + s * Bn; hoff = hsh + s * Bn;
    Bte = ws1c + (size_t)s * Hn * Dn; be = bs1 + (size_t)s * Hn;
  }
  int mbase = mt * 128;
  if (mbase >= M) return;
  int n0 = nt * 256;

  __shared__ __align__(16) unsigned short shb[36864];

  int tid = threadIdx.x;
  int lane = tid & 63, wv = tid >> 6;
  int wm = wv >> 2, wn = wv & 3;
  int l31 = lane & 31, l5 = lane >> 5;
  int rswA = (l31 >> 1) & 3;

  int scol = (((tid & 3) ^ ((tid >> 3) & 3)) * 8);
  int mi = mbase + (tid >> 2);
  if (mi > M - 1) mi = M - 1;
  int grow = slotRow[off + mi];
  const unsigned short* agp = xb + (size_t)grow * Dn + scol;
  const unsigned short* Bnt = Bte + (size_t)nt * 262144;   // 128*256*8
  const unsigned short* bgp0 = Bnt + (((size_t)(tid >> 8) * 256 + (tid & 255)) << 3);
  const unsigned short* bgp1 = bgp0 + 4096;                // chunks +2

  f32x16 acc[2][2];
#pragma unroll
  for (int i = 0; i < 2; i++)
#pragma unroll
    for (int j = 0; j < 2; j++)
#pragma unroll
      for (int q = 0; q < 16; q++) acc[i][j][q] = 0.f;

  auto STAGE = [&](int slot, int tt) {
    int so = slot * 12288;
    gload16(agp + tt * 32, &shb[so + wv * 512]);
    gload16(bgp0 + tt * 8192, &shb[so + 4096 + wv * 512]);
    gload16(bgp1 + tt * 8192, &shb[so + 8192 + wv * 512]);
  };
  auto COMPUTE = [&](int slot) {
    int so = slot * 12288;
#pragma unroll
    for (int kk = 0; kk < 2; kk++) {
      int cA = (((kk * 2 + l5) ^ rswA) * 8);
      short8 a0 = *(const short8*)&shb[so + (wm * 64 + l31) * 32 + cA];
      short8 a1 = *(const short8*)&shb[so + (wm * 64 + 32 + l31) * 32 + cA];
      int cB = (kk * 2 + l5) * 256;
      short8 b0 = *(const short8*)&shb[so + 4096 + (cB + wn * 64 + l31) * 8];
      short8 b1 = *(const short8*)&shb[so + 4096 + (cB + wn * 64 + 32 + l31) * 8];
      acc[0][0] = __builtin_amdgcn_mfma_f32_32x32x16_bf16(a0, b0, acc[0][0], 0, 0, 0);
      acc[0][1] = __builtin_amdgcn_mfma_f32_32x32x16_bf16(a0, b1, acc[0][1], 0, 0, 0);
      acc[1][0] = __builtin_amdgcn_mfma_f32_32x32x16_bf16(a1, b0, acc[1][0], 0, 0, 0);
      acc[1][1] = __builtin_amdgcn_mfma_f32_32x32x16_bf16(a1, b1, acc[1][1], 0, 0, 0);
    }
  };

  const int NT = Dn >> 5;   // 32
  int sA = 0, sB = 1, sC = 2;
  STAGE(0, 0);
  STAGE(1, 1);
  for (int t = 0; t < NT; ++t) {
    int tn = (t + 2 < NT) ? (t + 2) : (NT - 1);
    STAGE(sC, tn);
    asm volatile("s_waitcnt vmcnt(6)" ::: "memory");
    asm volatile("s_barrier" ::: "memory");
    COMPUTE(sA);
    asm volatile("s_barrier" ::: "memory");
    int tmp = sA; sA = sB; sB = sC; sC = tmp;
  }

  float bev[2];
#pragma unroll
  for (int g = 0; g < 2; g++) bev[g] = be[n0 + wn * 64 + g * 32 + l31];
#pragma unroll
  for (int i = 0; i < 2; i++) {
#pragma unroll
    for (int reg = 0; reg < 16; reg++) {
      int rr = (reg & 3) + 8 * (reg >> 2) + 4 * l5;
      int m = mbase + wm * 64 + i * 32 + rr;
      if (m < M) {
        size_t hrow = (size_t)(hoff + m) * Hn;
#pragma unroll
        for (int g = 0; g < 2; g++) {
          int n = n0 + wn * 64 + g * 32 + l31;
          float v = acc[i][g][reg] + bev[g];
          h[hrow + n] = f2bf(fmaxf(v, 0.f));
        }
      }
    }
  }
}

// experts only: writes weighted partials to Y rows r*2+s
__global__ __launch_bounds__(512, 4) void gemm2_u(
    const unsigned short* __restrict__ hin,
    const unsigned short* __restrict__ w2c,
    const float* __restrict__ b2,
    const int* __restrict__ cnt, const float* __restrict__ slotW,
    const int* __restrict__ slotDst, float* __restrict__ Y) {
  int total = gridDim.x;
  int gid = blockIdx.x;
  int swz = (gid & 7) * (total >> 3) + (gid >> 3);
  int u = swz >> 8;                     // per_e = 4*64 = 256
  int rem = swz & 255;
  int mt = rem & 63;
  int nt = rem >> 6;

  int M = cnt[u], off = 0;
  for (int i = 0; i < u; i++) off += cnt[i];
  int hoff = off;
  const unsigned short* Bte = w2c + (size_t)u * On * Hn;
  const float* be = b2 + (size_t)u * On;

  int mbase = mt * 128;
  if (mbase >= M) return;
  int n0 = nt * 256;

  __shared__ __align__(16) unsigned short shb[36864];

  int tid = threadIdx.x;
  int lane = tid & 63, wv = tid >> 6;
  int wm = wv >> 2, wn = wv & 3;
  int l31 = lane & 31, l5 = lane >> 5;
  int rswA = (l31 >> 1) & 3;

  int scol = (((tid & 3) ^ ((tid >> 3) & 3)) * 8);
  int mi = mbase + (tid >> 2);
  if (mi > M - 1) mi = M - 1;
  const unsigned short* agp = hin + (size_t)(hoff + mi) * Hn + scol;
  const unsigned short* Bnt = Bte + (size_t)nt * 1048576;   // 512*256*8
  const unsigned short* bgp0 = Bnt + (((size_t)(tid >> 8) * 256 + (tid & 255)) << 3);
  const unsigned short* bgp1 = bgp0 + 4096;

  f32x16 acc[2][2];
#pragma unroll
  for (int i = 0; i < 2; i++)
#pragma unroll
    for (int j = 0; j < 2; j++)
#pragma unroll
      for (int q = 0; q < 16; q++) acc[i][j][q] = 0.f;

  auto STAGE = [&](int slot, int tt) {
    int so = slot * 12288;
    gload16(agp + tt * 32, &shb[so + wv * 512]);
    gload16(bgp0 + tt * 8192, &shb[so + 4096 + wv * 512]);
    gload16(bgp1 + tt * 8192, &shb[so + 8192 + wv * 512]);
  };
  auto COMPUTE = [&](int slot) {
    int so = slot * 12288;
#pragma unroll
    for (int kk = 0; kk < 2; kk++) {
      int cA = (((kk * 2 + l5) ^ rswA) * 8);
      short8 a0 = *(const short8*)&shb[so + (wm * 64 + l31) * 32 + cA];
      short8 a1 = *(const short8*)&shb[so + (wm * 64 + 32 + l31) * 32 + cA];
      int cB = (kk * 2 + l5) * 256;
      short8 b0 = *(const short8*)&shb[so + 4096 + (cB + wn * 64 + l31) * 8];
      short8 b1 = *(const short8*)&shb[so + 4096 + (cB + wn * 64 + 32 + l31) * 8];
      acc[0][0] = __builtin_amdgcn_mfma_f32_32x32x16_bf16(a0, b0, acc[0][0], 0, 0, 0);
      acc[0][1] = __builtin_amdgcn_mfma_f32_32x32x16_bf16(a0, b1, acc[0][1], 0, 0, 0);
      acc[1][0] = __builtin_amdgcn_mfma_f32_32x32x16_bf16(a1, b0, acc[1][0], 0, 0, 0);
      acc[1][1] = __builtin_amdgcn_mfma_f32_32x32x16_bf16(a1, b1, acc[1][1], 0, 0, 0);
    }
  };

  const int NT = Hn >> 5;   // 128
  int sA = 0, sB = 1, sC = 2;
  STAGE(0, 0);
  STAGE(1, 1);
  for (int t = 0; t < NT; ++t) {
    int tn = (t + 2 < NT) ? (t + 2) : (NT - 1);
    STAGE(sC, tn);
    asm volatile("s_waitcnt vmcnt(6)" ::: "memory");
    asm volatile("s_barrier" ::: "memory");
    COMPUTE(sA);
    asm volatile("s_barrier" ::: "memory");
    int tmp = sA; sA = sB; sB = sC; sC = tmp;
  }

  float bev[2];
#pragma unroll
  for (int g = 0; g < 2; g++) bev[g] = be[n0 + wn * 64 + g * 32 + l31];
#pragma unroll
  for (int i = 0; i < 2; i++) {
#pragma unroll
    for (int reg = 0; reg < 16; reg++) {
      int rr = (reg & 3) + 8 * (reg >> 2) + 4 * l5;
      int m = mbase + wm * 64 + i * 32 + rr;
      if (m < M) {
        float wgt = slotW[off + m];
        size_t yrow = (size_t)slotDst[off + m] * On;
#pragma unroll
        for (int g = 0; g < 2; g++) {
          int n = n0 + wn * 64 + g * 32 + l31;
          Y[yrow + n] = wgt * (acc[i][g][reg] + bev[g]);
        }
      }
    }
  }
}

// ==== merged shared-expert gemm2: 128x128 tile, both s per block, final sum ====
// Same proven loop schedule; 2 loads/tile -> counted hand-off vmcnt(4).
// Two sequential pipelined K-loops (s=0 then s=1); vmcnt counts oldest-first
// so the seam needs no special handling.  Epilogue: out = w_s0*(acc0+b) +
// w_s1*(acc1+b) + Y[r*2] + Y[r*2+1]   (final_k eliminated).
__global__ __launch_bounds__(512, 4) void gemm2s_m(
    const unsigned short* __restrict__ hin,     // rows 0..8191 s0, 8192..16383 s1
    const unsigned short* __restrict__ ws2c,
    const float* __restrict__ bs2, const float* __restrict__ rw,
    const float* __restrict__ Y, float* __restrict__ outp) {
  int total = gridDim.x;                        // 512
  int gid = blockIdx.x;
  int swz = (gid & 7) * (total >> 3) + (gid >> 3);
  int mt = swz & 63;
  int nt = swz >> 6;                            // 0..7
  int mbase = mt * 128;
  int n0 = nt * 128;

  __shared__ __align__(16) unsigned short shb[24576];   // 3 x (A 4096 + B 4096)

  int tid = threadIdx.x;
  int lane = tid & 63, wv = tid >> 6;
  int wm = wv >> 2, wn = wv & 3;
  int l31 = lane & 31, l5 = lane >> 5;
  int rswA = (l31 >> 1) & 3;

  int scol = (((tid & 3) ^ ((tid >> 3) & 3)) * 8);
  const unsigned short* agp0 = hin + (size_t)(mbase + (tid >> 2)) * Hn + scol;
  const unsigned short* agp1 = agp0 + (size_t)8192 * Hn;
  size_t bcol = (((size_t)(tid >> 7) * 256 + (nt & 1) * 128 + (tid & 127)) << 3);
  const unsigned short* bgp0 = ws2c + (size_t)(nt >> 1) * 1048576 + bcol;
  const unsigned short* bgp1 = bgp0 + (size_t)Hn * On;

  f32x16 acc0[2], acc1[2];
#pragma unroll
  for (int i = 0; i < 2; i++)
#pragma unroll
    for (int q = 0; q < 16; q++) { acc0[i][q] = 0.f; acc1[i][q] = 0.f; }

  auto STAGE = [&](int slot, int tt, const unsigned short* ag, const unsigned short* bg) {
    int so = slot * 8192;
    gload16(ag + tt * 32, &shb[so + wv * 512]);
    gload16(bg + (size_t)tt * 8192, &shb[so + 4096 + wv * 512]);
  };
  auto COMPUTE = [&](int slot, f32x16 (&ac)[2]) {
    int so = slot * 8192;
#pragma unroll
    for (int kk = 0; kk < 2; kk++) {
      int cA = (((kk * 2 + l5) ^ rswA) * 8);
      short8 a0 = *(const short8*)&shb[so + (wm * 64 + l31) * 32 + cA];
      short8 a1 = *(const short8*)&shb[so + (wm * 64 + 32 + l31) * 32 + cA];
      int cB = (kk * 2 + l5) * 128;
      short8 b0 = *(const short8*)&shb[so + 4096 + (cB + wn * 32 + l31) * 8];
      ac[0] = __builtin_amdgcn_mfma_f32_32x32x16_bf16(a0, b0, ac[0], 0, 0, 0);
      ac[1] = __builtin_amdgcn_mfma_f32_32x32x16_bf16(a1, b0, ac[1], 0, 0, 0);
    }
  };

  {
    int sA = 0, sB = 1, sC = 2;
    STAGE(0, 0, agp0, bgp0);
    STAGE(1, 1, agp0, bgp0);
    for (int t = 0; t < 128; ++t) {
      int tn = (t + 2 < 128) ? (t + 2) : 127;
      STAGE(sC, tn, agp0, bgp0);
      asm volatile("s_waitcnt vmcnt(4)" ::: "memory");
      asm volatile("s_barrier" ::: "memory");
      COMPUTE(sA, acc0);
      asm volatile("s_barrier" ::: "memory");
      int tmp = sA; sA = sB; sB = sC; sC = tmp;
    }
  }
  {
    int sA = 0, sB = 1, sC = 2;
    STAGE(0, 0, agp1, bgp1);
    STAGE(1, 1, agp1, bgp1);
    for (int t = 0; t < 128; ++t) {
      int tn = (t + 2 < 128) ? (t + 2) : 127;
      STAGE(sC, tn, agp1, bgp1);
      asm volatile("s_waitcnt vmcnt(4)" ::: "memory");
      asm volatile("s_barrier" ::: "memory");
      COMPUTE(sA, acc1);
      asm volatile("s_barrier" ::: "memory");
      int tmp = sA; sA = sB; sB = sC; sC = tmp;
    }
  }

  int n = n0 + wn * 32 + l31;
  float be0 = bs2[n];
  float be1 = bs2[On + n];
#pragma unroll
  for (int i = 0; i < 2; i++) {
#pragma unroll
    for (int reg = 0; reg < 16; reg++) {
      int rr = (reg & 3) + 8 * (reg >> 2) + 4 * l5;
      int m = mbase + wm * 64 + i * 32 + rr;
      float w0 = rw[m * 4 + 2], w1 = rw[m * 4 + 3];
      float v = w0 * (acc0[i][reg] + be0) + w1 * (acc1[i][reg] + be1)
              + Y[((size_t)m * 2 + 0) * On + n] + Y[((size_t)m * 2 + 1) * On + n];
      outp[(size_t)m * On + n] = v;
    }
  }
}

extern "C" void kernel_launch(void* const* d_in, const int* in_sizes, int n_in,
                              void* d_out, int out_size, void* d_ws, size_t ws_size,
                              hipStream_t stream) {
  const float* x   = (const float*)d_in[0];
  const float* W1  = (const float*)d_in[1];
  const float* b1  = (const float*)d_in[2];
  const float* W2  = (const float*)d_in[3];
  const float* b2  = (const float*)d_in[4];
  const float* Ws1 = (const float*)d_in[5];
  const float* bs1 = (const float*)d_in[6];
  const float* Ws2 = (const float*)d_in[7];
  const float* bs2 = (const float*)d_in[8];
  const float* Wg  = (const float*)d_in[9];
  const float* bg  = (const float*)d_in[10];
  float* out = (float*)d_out;

  // FALLBACK-ONLY workspace plan (hbuf = 16384 rows, reused expert->shared).
  char* w = (char*)d_ws;
  size_t p = 0;
  auto alloc = [&](size_t n) { char* r = w + p; p = (p + n + 255) & ~(size_t)255; return r; };
  unsigned short* xb   = (unsigned short*)alloc((size_t)Bn * Dn * 2);
  unsigned short* w1t  = (unsigned short*)alloc((size_t)En * Hn * Dn * 2);
  unsigned short* w2t  = (unsigned short*)alloc((size_t)En * On * Hn * 2);
  unsigned short* ws1t = (unsigned short*)alloc((size_t)Sn * Hn * Dn * 2);
  unsigned short* ws2t = (unsigned short*)alloc((size_t)Sn * On * Hn * 2);
  unsigned short* hbuf = (unsigned short*)alloc((size_t)16384 * Hn * 2);
  float* Y             = (float*)alloc((size_t)Bn * 2 * On * 4);   // expert partials
  float* rw            = (float*)alloc((size_t)Bn * 4 * 4);
  int* ri              = (int*)alloc((size_t)Bn * 2 * 4);
  int* ctrl            = (int*)alloc(256);
  int* slot_row        = (int*)alloc((size_t)32768 * 4);
  float* slot_w        = (float*)alloc((size_t)32768 * 4);
  int* slot_dst        = (int*)alloc((size_t)32768 * 4);
  if (p > ws_size) return;   // ws too small

  int* cnt  = ctrl;
  int* cnt2 = ctrl + 8;

  hipMemsetAsync(ctrl, 0, 64, stream);
  gate_k<<<2048, 256, 0, stream>>>(x, Wg, bg, xb, rw, ri);
  tcvt_all<<<10240, 256, 0, stream>>>(W1, W2, Ws1, Ws2, w1t, w2t, ws1t, ws2t);
  count_k<<<16, 256, 0, stream>>>(ri, cnt);
  build_k<<<32, 256, 0, stream>>>(rw, ri, cnt, cnt2, slot_row, slot_w, slot_dst);

  // experts (u=0..7): hbuf rows 0..16383 -> Y partials
  gemm1_u<<<8 * 1024, 512, 0, stream>>>(xb, w1t, ws1t, b1, bs1, cnt, slot_row,
                                        hbuf, 0, 0);
  gemm2_u<<<8 * 256, 512, 0, stream>>>(hbuf, w2t, b2, cnt, slot_w, slot_dst, Y);
  // shared (u=8..9): hbuf rows reused (s0: 0..8191, s1: 8192..16383)
  gemm1_u<<<2 * 1024, 512, 0, stream>>>(xb, w1t, ws1t, b1, bs1, cnt, slot_row,
                                        hbuf, 8, 0);
  // merged shared gemm2 + final combine
  gemm2s_m<<<512, 512, 0, stream>>>(hbuf, ws2t, bs2, rw, Y, out);
}

// Round 6
// 855.605 us; speedup vs baseline: 1.7040x; 1.0047x over previous
//
#include <hip/hip_runtime.h>
#include <stdint.h>

#define Bn 8192
#define Dn 1024
#define Hn 4096
#define On 1024
#define En 8
#define Sn 2

typedef __attribute__((ext_vector_type(8))) short short8;
typedef __attribute__((ext_vector_type(4))) float f32x4;
typedef __attribute__((ext_vector_type(16))) float f32x16;

__device__ __forceinline__ unsigned short f2bf(float f) {
  unsigned int u = __float_as_uint(f);
  u += 0x7fff + ((u >> 16) & 1);   // round-to-nearest-even
  return (unsigned short)(u >> 16);
}

__device__ __forceinline__ void gload16(const void* g, void* l) {
  __builtin_amdgcn_global_load_lds(
      (const __attribute__((address_space(1))) unsigned int*)g,
      (__attribute__((address_space(3))) unsigned int*)l, 16, 0, 0);
}

// ---------------- gate: single-pass x read, fused bf16 convert ----------------
// R24: convert folded into the dot loop (x read once, not twice).  Stores of
// f2bf are 128B/wave contiguous per iteration; loads coalesced per-iteration.
__global__ __launch_bounds__(256) void gate_k(
    const float* __restrict__ x, const float* __restrict__ Wg,
    const float* __restrict__ bg, unsigned short* __restrict__ xb,
    float* __restrict__ rw, int* __restrict__ ri) {
  __shared__ __align__(16) float wgs[Dn * 10];
  for (int i = threadIdx.x; i < 2560; i += 256)
    ((float4*)wgs)[i] = ((const float4*)Wg)[i];
  __syncthreads();
  int lane = threadIdx.x & 63, wave = threadIdx.x >> 6;
  int r = blockIdx.x * 4 + wave;
  const float* xr = x + (size_t)r * Dn;
  unsigned short* xbr = xb + (size_t)r * Dn;
  float p[10];
#pragma unroll
  for (int j = 0; j < 10; j++) p[j] = 0.f;
  for (int d = lane; d < Dn; d += 64) {
    float xv = xr[d];
    xbr[d] = f2bf(xv);
#pragma unroll
    for (int j = 0; j < 10; j++) p[j] += xv * wgs[d * 10 + j];
  }
#pragma unroll
  for (int off = 32; off; off >>= 1)
#pragma unroll
    for (int j = 0; j < 10; j++) p[j] += __shfl_xor(p[j], off);
  float mx = -1e30f;
#pragma unroll
  for (int j = 0; j < 10; j++) { p[j] += bg[j]; mx = fmaxf(mx, p[j]); }
  float s = 0.f;
#pragma unroll
  for (int j = 0; j < 10; j++) { p[j] = expf(p[j] - mx); s += p[j]; }
  float inv = 1.f / s;
  int i0 = 2, i1 = 2; float v0 = -1e30f, v1 = -1e30f;
#pragma unroll
  for (int j = 2; j < 10; j++) {
    float v = p[j];
    if (v > v0) { v1 = v0; i1 = i0; v0 = v; i0 = j; }
    else if (v > v1) { v1 = v; i1 = j; }
  }
  if (lane == 0) {
    rw[r * 4 + 0] = v0 * inv;
    rw[r * 4 + 1] = v1 * inv;
    rw[r * 4 + 2] = p[0] * inv;
    rw[r * 4 + 3] = p[1] * inv;
    ri[r * 2 + 0] = i0 - 2;
    ri[r * 2 + 1] = i1 - 2;
  }
}

// ---------------- count: 16 blocks, register histograms, 128 atomics total ----------------
__global__ __launch_bounds__(256) void count_k(const int* __restrict__ ri,
                                               int* __restrict__ cnt) {
  int c[8];
#pragma unroll
  for (int j = 0; j < 8; j++) c[j] = 0;
  int base = blockIdx.x * 1024;
  for (int i = threadIdx.x; i < 1024; i += 256) {
    int e = ri[base + i];
#pragma unroll
    for (int j = 0; j < 8; j++) c[j] += (e == j) ? 1 : 0;
  }
#pragma unroll
  for (int j = 0; j < 8; j++)
#pragma unroll
    for (int off = 32; off; off >>= 1) c[j] += __shfl_xor(c[j], off);
  __shared__ int sc[4][8];
  int wv = threadIdx.x >> 6, lane = threadIdx.x & 63;
  if (lane == 0)
#pragma unroll
    for (int j = 0; j < 8; j++) sc[wv][j] = c[j];
  __syncthreads();
  if (threadIdx.x < 8)
    atomicAdd(&cnt[threadIdx.x], sc[0][threadIdx.x] + sc[1][threadIdx.x] +
                                 sc[2][threadIdx.x] + sc[3][threadIdx.x]);
}

// ---------------- weight transposes -> CHUNK-MAJOR layout, NO LDS ----------------
// out[e][nt = n/256][c = k/8][r = n%256][8]  (bf16)
// R24: direct transpose.  For fixed k-row j, the wave's 64 lanes read 64
// consecutive floats (256B coalesced); the short8 write is 1KB/wave
// contiguous.  Drops the 128x65 LDS tile, 2 barriers, and bank conflicts.
__global__ __launch_bounds__(256) void tcvt_all(
    const float* __restrict__ W1, const float* __restrict__ W2,
    const float* __restrict__ Ws1, const float* __restrict__ Ws2,
    unsigned short* __restrict__ w1t, unsigned short* __restrict__ w2t,
    unsigned short* __restrict__ ws1t, unsigned short* __restrict__ ws2t) {
  int bid = blockIdx.x;
  int u = bid >> 9, r = bid & 511;   // 512 tiles per unit
  const float* in; unsigned short* out; int Kd, Nd;
  if (u < 8)       { Kd = Dn; Nd = Hn; in = W1  + (size_t)u * Dn * Hn;        out = w1t  + (size_t)u * Dn * Hn; }
  else if (u < 16) { Kd = Hn; Nd = On; in = W2  + (size_t)(u - 8) * Hn * On;  out = w2t  + (size_t)(u - 8) * Hn * On; }
  else if (u < 18) { Kd = Dn; Nd = Hn; in = Ws1 + (size_t)(u - 16) * Dn * Hn; out = ws1t + (size_t)(u - 16) * Dn * Hn; }
  else             { Kd = Hn; Nd = On; in = Ws2 + (size_t)(u - 18) * Hn * On; out = ws2t + (size_t)(u - 18) * Hn * On; }
  int by, bx;
  if (Kd == Dn) { by = (r & 7) * 128;  bx = (r >> 3) * 64; }
  else          { by = (r & 31) * 128; bx = (r >> 5) * 64; }
  int tid = threadIdx.x;
  int nl = tid & 63;            // column within 64-wide tile (per-wave coalesced)
  int kq = tid >> 6;            // wave id 0..3
  int KC = Kd >> 3;
  int ng = bx + nl;
#pragma unroll
  for (int p = 0; p < 4; p++) {
    int kgi = p * 4 + kq;       // k-group 0..15
    int kg = kgi * 8;
    short8 v;
#pragma unroll
    for (int j = 0; j < 8; j++)
      v[j] = (short)f2bf(in[(size_t)(by + kg + j) * Nd + ng]);
    size_t o = ((((size_t)(ng >> 8) * KC + (by >> 3) + kgi) * 256 + (ng & 255)) << 3);
    *(short8*)&out[o] = v;
  }
}

// ---------------- build: LDS ranks + 8 global atomics/block ----------------
__global__ __launch_bounds__(256) void build_k(
    const float* __restrict__ rw, const int* __restrict__ ri,
    const int* __restrict__ cnt, int* __restrict__ cnt2,
    int* __restrict__ slot_row, float* __restrict__ slot_w,
    int* __restrict__ slot_dst) {
  __shared__ int lcnt[8], lbase[8];
  int tid = threadIdx.x;
  if (tid < 8) lcnt[tid] = 0;
  __syncthreads();
  int r = blockIdx.x * 256 + tid;
  int e0 = ri[r * 2 + 0], e1 = ri[r * 2 + 1];
  int rk0 = atomicAdd(&lcnt[e0], 1);
  int rk1 = atomicAdd(&lcnt[e1], 1);
  __syncthreads();
  if (tid < 8) lbase[tid] = atomicAdd(&cnt2[tid], lcnt[tid]);
  __syncthreads();
  int off0 = 0, off1 = 0;
#pragma unroll
  for (int i = 0; i < 8; i++) {
    int ci = cnt[i];
    off0 += (i < e0) ? ci : 0;
    off1 += (i < e1) ? ci : 0;
  }
  int s0 = off0 + lbase[e0] + rk0;
  int s1 = off1 + lbase[e1] + rk1;
  slot_row[s0] = r; slot_w[s0] = rw[r * 4 + 0]; slot_dst[s0] = r * 4 + 0;
  slot_row[s1] = r; slot_w[s1] = rw[r * 4 + 1]; slot_dst[s1] = r * 4 + 1;
#pragma unroll
  for (int s = 0; s < 2; s++) {
    int slot = 16384 + s * Bn + r;
    slot_row[slot] = r;
    slot_w[slot] = rw[r * 4 + 2 + s];
    slot_dst[slot] = r * 4 + 2 + s;
  }
}

// ==== 128x256 BK=32 8-wave GEMM: 32x32 MFMA, hybrid LDS (R0/R18 FROZEN) ====
// A: row-major LDS [128][4 chunks][8] w/ XOR swizzle chunk=c^((l31>>1)&3)
// B: chunk-major LDS [4c][256][8] staged from CHUNK-MAJOR GLOBAL (tcvt_all)
// Loop: STAGE(sC,t+2) -> vmcnt(6) -> s_barrier -> COMPUTE(sA) -> s_barrier.
// DO NOT TOUCH THE LOOP: depth-1 (R22) broke cohort lockstep -> FETCH 2.6x;
// phase-split (R19) serialized ds_read vs MFMA; atomics epilogue (R21) +24us;
// merged 128-wide shared gemm2 (R23) +10us.  2 blocks/CU is reg+LDS capped
// (56 VGPR + 64 AGPR = 120/lane -> 16 waves/CU; 72KB LDS).
// C/D layout (m74/m101): col=lane&31, row=(reg&3)+8*(reg>>2)+4*(lane>>5).

__global__ __launch_bounds__(512, 4) void gemm1_u(
    const unsigned short* __restrict__ xb,
    const unsigned short* __restrict__ w1c, const unsigned short* __restrict__ ws1c,
    const float* __restrict__ b1, const float* __restrict__ bs1,
    const int* __restrict__ cnt, const int* __restrict__ slotRow,
    unsigned short* __restrict__ h, int ubase, int hsh) {
  int total = gridDim.x;
  int gid = blockIdx.x;
  int swz = (gid & 7) * (total >> 3) + (gid >> 3);
  int u = ubase + (swz >> 10);          // per_e = 16*64 = 1024
  int rem = swz & 1023;
  int mt = rem & 63;
  int nt = rem >> 6;

  int M, off, hoff;
  const unsigned short* Bte; const float* be;
  if (u < 8) {
    M = cnt[u]; off = 0;
    for (int i = 0; i < u; i++) off += cnt[i];
    hoff = off;
    Bte = w1c + (size_t)u * Hn * Dn; be = b1 + (size_t)u * Hn;
  } else {
    int s = u - 8;
    M = Bn; off = 16384 + s * Bn; hoff = hsh + s * Bn;
    Bte = ws1c + (size_t)s * Hn * Dn; be = bs1 + (size_t)s * Hn;
  }
  int mbase = mt * 128;
  if (mbase >= M) return;
  int n0 = nt * 256;

  __shared__ __align__(16) unsigned short shb[36864];

  int tid = threadIdx.x;
  int lane = tid & 63, wv = tid >> 6;
  int wm = wv >> 2, wn = wv & 3;
  int l31 = lane & 31, l5 = lane >> 5;
  int rswA = (l31 >> 1) & 3;

  int scol = (((tid & 3) ^ ((tid >> 3) & 3)) * 8);
  int mi = mbase + (tid >> 2);
  if (mi > M - 1) mi = M - 1;
  int grow = slotRow[off + mi];
  const unsigned short* agp = xb + (size_t)grow * Dn + scol;
  const unsigned short* Bnt = Bte + (size_t)nt * 262144;   // 128*256*8
  const unsigned short* bgp0 = Bnt + (((size_t)(tid >> 8) * 256 + (tid & 255)) << 3);
  const unsigned short* bgp1 = bgp0 + 4096;                // chunks +2

  f32x16 acc[2][2];
#pragma unroll
  for (int i = 0; i < 2; i++)
#pragma unroll
    for (int j = 0; j < 2; j++)
#pragma unroll
      for (int q = 0; q < 16; q++) acc[i][j][q] = 0.f;

  auto STAGE = [&](int slot, int tt) {
    int so = slot * 12288;
    gload16(agp + tt * 32, &shb[so + wv * 512]);
    gload16(bgp0 + tt * 8192, &shb[so + 4096 + wv * 512]);
    gload16(bgp1 + tt * 8192, &shb[so + 8192 + wv * 512]);
  };
  auto COMPUTE = [&](int slot) {
    int so = slot * 12288;
#pragma unroll
    for (int kk = 0; kk < 2; kk++) {
      int cA = (((kk * 2 + l5) ^ rswA) * 8);
      short8 a0 = *(const short8*)&shb[so + (wm * 64 + l31) * 32 + cA];
      short8 a1 = *(const short8*)&shb[so + (wm * 64 + 32 + l31) * 32 + cA];
      int cB = (kk * 2 + l5) * 256;
      short8 b0 = *(const short8*)&shb[so + 4096 + (cB + wn * 64 + l31) * 8];
      short8 b1 = *(const short8*)&shb[so + 4096 + (cB + wn * 64 + 32 + l31) * 8];
      acc[0][0] = __builtin_amdgcn_mfma_f32_32x32x16_bf16(a0, b0, acc[0][0], 0, 0, 0);
      acc[0][1] = __builtin_amdgcn_mfma_f32_32x32x16_bf16(a0, b1, acc[0][1], 0, 0, 0);
      acc[1][0] = __builtin_amdgcn_mfma_f32_32x32x16_bf16(a1, b0, acc[1][0], 0, 0, 0);
      acc[1][1] = __builtin_amdgcn_mfma_f32_32x32x16_bf16(a1, b1, acc[1][1], 0, 0, 0);
    }
  };

  const int NT = Dn >> 5;   // 32
  int sA = 0, sB = 1, sC = 2;
  STAGE(0, 0);
  STAGE(1, 1);
  for (int t = 0; t < NT; ++t) {
    int tn = (t + 2 < NT) ? (t + 2) : (NT - 1);
    STAGE(sC, tn);
    asm volatile("s_waitcnt vmcnt(6)" ::: "memory");
    asm volatile("s_barrier" ::: "memory");
    COMPUTE(sA);
    asm volatile("s_barrier" ::: "memory");
    int tmp = sA; sA = sB; sB = sC; sC = tmp;
  }

  float bev[2];
#pragma unroll
  for (int g = 0; g < 2; g++) bev[g] = be[n0 + wn * 64 + g * 32 + l31];
#pragma unroll
  for (int i = 0; i < 2; i++) {
#pragma unroll
    for (int reg = 0; reg < 16; reg++) {
      int rr = (reg & 3) + 8 * (reg >> 2) + 4 * l5;
      int m = mbase + wm * 64 + i * 32 + rr;
      if (m < M) {
        size_t hrow = (size_t)(hoff + m) * Hn;
#pragma unroll
        for (int g = 0; g < 2; g++) {
          int n = n0 + wn * 64 + g * 32 + l31;
          float v = acc[i][g][reg] + bev[g];
          h[hrow + n] = f2bf(fmaxf(v, 0.f));
        }
      }
    }
  }
}

__global__ __launch_bounds__(512, 4) void gemm2_u(
    const unsigned short* __restrict__ hin,
    const unsigned short* __restrict__ w2c, const unsigned short* __restrict__ ws2c,
    const float* __restrict__ b2, const float* __restrict__ bs2,
    const int* __restrict__ cnt, const float* __restrict__ slotW,
    const int* __restrict__ slotDst, float* __restrict__ Y, int ubase, int hsh) {
  int total = gridDim.x;
  int gid = blockIdx.x;
  int swz = (gid & 7) * (total >> 3) + (gid >> 3);
  int u = ubase + (swz >> 8);           // per_e = 4*64 = 256
  int rem = swz & 255;
  int mt = rem & 63;
  int nt = rem >> 6;

  int M, off, hoff;
  const unsigned short* Bte; const float* be;
  if (u < 8) {
    M = cnt[u]; off = 0;
    for (int i = 0; i < u; i++) off += cnt[i];
    hoff = off;
    Bte = w2c + (size_t)u * On * Hn; be = b2 + (size_t)u * On;
  } else {
    int s = u - 8;
    M = Bn; off = 16384 + s * Bn; hoff = hsh + s * Bn;
    Bte = ws2c + (size_t)s * On * Hn; be = bs2 + (size_t)s * On;
  }
  int mbase = mt * 128;
  if (mbase >= M) return;
  int n0 = nt * 256;

  __shared__ __align__(16) unsigned short shb[36864];

  int tid = threadIdx.x;
  int lane = tid & 63, wv = tid >> 6;
  int wm = wv >> 2, wn = wv & 3;
  int l31 = lane & 31, l5 = lane >> 5;
  int rswA = (l31 >> 1) & 3;

  int scol = (((tid & 3) ^ ((tid >> 3) & 3)) * 8);
  int mi = mbase + (tid >> 2);
  if (mi > M - 1) mi = M - 1;
  const unsigned short* agp = hin + (size_t)(hoff + mi) * Hn + scol;
  const unsigned short* Bnt = Bte + (size_t)nt * 1048576;   // 512*256*8
  const unsigned short* bgp0 = Bnt + (((size_t)(tid >> 8) * 256 + (tid & 255)) << 3);
  const unsigned short* bgp1 = bgp0 + 4096;

  f32x16 acc[2][2];
#pragma unroll
  for (int i = 0; i < 2; i++)
#pragma unroll
    for (int j = 0; j < 2; j++)
#pragma unroll
      for (int q = 0; q < 16; q++) acc[i][j][q] = 0.f;

  auto STAGE = [&](int slot, int tt) {
    int so = slot * 12288;
    gload16(agp + tt * 32, &shb[so + wv * 512]);
    gload16(bgp0 + tt * 8192, &shb[so + 4096 + wv * 512]);
    gload16(bgp1 + tt * 8192, &shb[so + 8192 + wv * 512]);
  };
  auto COMPUTE = [&](int slot) {
    int so = slot * 12288;
#pragma unroll
    for (int kk = 0; kk < 2; kk++) {
      int cA = (((kk * 2 + l5) ^ rswA) * 8);
      short8 a0 = *(const short8*)&shb[so + (wm * 64 + l31) * 32 + cA];
      short8 a1 = *(const short8*)&shb[so + (wm * 64 + 32 + l31) * 32 + cA];
      int cB = (kk * 2 + l5) * 256;
      short8 b0 = *(const short8*)&shb[so + 4096 + (cB + wn * 64 + l31) * 8];
      short8 b1 = *(const short8*)&shb[so + 4096 + (cB + wn * 64 + 32 + l31) * 8];
      acc[0][0] = __builtin_amdgcn_mfma_f32_32x32x16_bf16(a0, b0, acc[0][0], 0, 0, 0);
      acc[0][1] = __builtin_amdgcn_mfma_f32_32x32x16_bf16(a0, b1, acc[0][1], 0, 0, 0);
      acc[1][0] = __builtin_amdgcn_mfma_f32_32x32x16_bf16(a1, b0, acc[1][0], 0, 0, 0);
      acc[1][1] = __builtin_amdgcn_mfma_f32_32x32x16_bf16(a1, b1, acc[1][1], 0, 0, 0);
    }
  };

  const int NT = Hn >> 5;   // 128
  int sA = 0, sB = 1, sC = 2;
  STAGE(0, 0);
  STAGE(1, 1);
  for (int t = 0; t < NT; ++t) {
    int tn = (t + 2 < NT) ? (t + 2) : (NT - 1);
    STAGE(sC, tn);
    asm volatile("s_waitcnt vmcnt(6)" ::: "memory");
    asm volatile("s_barrier" ::: "memory");
    COMPUTE(sA);
    asm volatile("s_barrier" ::: "memory");
    int tmp = sA; sA = sB; sB = sC; sC = tmp;
  }

  float bev[2];
#pragma unroll
  for (int g = 0; g < 2; g++) bev[g] = be[n0 + wn * 64 + g * 32 + l31];
#pragma unroll
  for (int i = 0; i < 2; i++) {
#pragma unroll
    for (int reg = 0; reg < 16; reg++) {
      int rr = (reg & 3) + 8 * (reg >> 2) + 4 * l5;
      int m = mbase + wm * 64 + i * 32 + rr;
      if (m < M) {
        float wgt = slotW[off + m];
        size_t yrow = (size_t)slotDst[off + m] * On;
#pragma unroll
        for (int g = 0; g < 2; g++) {
          int n = n0 + wn * 64 + g * 32 + l31;
          Y[yrow + n] = wgt * (acc[i][g][reg] + bev[g]);
        }
      }
    }
  }
}

__global__ void final_k(const float* __restrict__ Y, float* __restrict__ out) {
  int i = blockIdx.x * 256 + threadIdx.x;   // float4 index over Bn*On/4, exact
  int b = i >> 8;
  int c = i & 255;
  const float4* y = (const float4*)Y;
  float4 a0 = y[((size_t)b * 4 + 0) * 256 + c];
  float4 a1 = y[((size_t)b * 4 + 1) * 256 + c];
  float4 a2 = y[((size_t)b * 4 + 2) * 256 + c];
  float4 a3 = y[((size_t)b * 4 + 3) * 256 + c];
  float4 o;
  o.x = a0.x + a1.x + a2.x + a3.x;
  o.y = a0.y + a1.y + a2.y + a3.y;
  o.z = a0.z + a1.z + a2.z + a3.z;
  o.w = a0.w + a1.w + a2.w + a3.w;
  ((float4*)out)[i] = o;
}

extern "C" void kernel_launch(void* const* d_in, const int* in_sizes, int n_in,
                              void* d_out, int out_size, void* d_ws, size_t ws_size,
                              hipStream_t stream) {
  const float* x   = (const float*)d_in[0];
  const float* W1  = (const float*)d_in[1];
  const float* b1  = (const float*)d_in[2];
  const float* W2  = (const float*)d_in[3];
  const float* b2  = (const float*)d_in[4];
  const float* Ws1 = (const float*)d_in[5];
  const float* bs1 = (const float*)d_in[6];
  const float* Ws2 = (const float*)d_in[7];
  const float* bs2 = (const float*)d_in[8];
  const float* Wg  = (const float*)d_in[9];
  const float* bg  = (const float*)d_in[10];
  float* out = (float*)d_out;

  // FALLBACK-ONLY workspace plan (hbuf = 16384 rows, reused expert->shared).
  char* w = (char*)d_ws;
  size_t p = 0;
  auto alloc = [&](size_t n) { char* r = w + p; p = (p + n + 255) & ~(size_t)255; return r; };
  unsigned short* xb   = (unsigned short*)alloc((size_t)Bn * Dn * 2);
  unsigned short* w1t  = (unsigned short*)alloc((size_t)En * Hn * Dn * 2);
  unsigned short* w2t  = (unsigned short*)alloc((size_t)En * On * Hn * 2);
  unsigned short* ws1t = (unsigned short*)alloc((size_t)Sn * Hn * Dn * 2);
  unsigned short* ws2t = (unsigned short*)alloc((size_t)Sn * On * Hn * 2);
  unsigned short* hbuf = (unsigned short*)alloc((size_t)16384 * Hn * 2);
  float* Y             = (float*)alloc((size_t)Bn * 4 * On * 4);
  float* rw            = (float*)alloc((size_t)Bn * 4 * 4);
  int* ri              = (int*)alloc((size_t)Bn * 2 * 4);
  int* ctrl            = (int*)alloc(256);
  int* slot_row        = (int*)alloc((size_t)32768 * 4);
  float* slot_w        = (float*)alloc((size_t)32768 * 4);
  int* slot_dst        = (int*)alloc((size_t)32768 * 4);
  if (p > ws_size) return;   // ws too small

  int* cnt  = ctrl;
  int* cnt2 = ctrl + 8;

  hipMemsetAsync(ctrl, 0, 64, stream);
  gate_k<<<2048, 256, 0, stream>>>(x, Wg, bg, xb, rw, ri);
  tcvt_all<<<10240, 256, 0, stream>>>(W1, W2, Ws1, Ws2, w1t, w2t, ws1t, ws2t);
  count_k<<<16, 256, 0, stream>>>(ri, cnt);
  build_k<<<32, 256, 0, stream>>>(rw, ri, cnt, cnt2, slot_row, slot_w, slot_dst);

  // experts (u=0..7): hbuf rows 0..16383, then consumed by gemm2
  gemm1_u<<<8 * 1024, 512, 0, stream>>>(xb, w1t, ws1t, b1, bs1, cnt, slot_row,
                                        hbuf, 0, 0);
  gemm2_u<<<8 * 256, 512, 0, stream>>>(hbuf, w2t, ws2t, b2, bs2, cnt, slot_w,
                                       slot_dst, Y, 0, 0);
  // shared (u=8..9): hbuf rows reused
  gemm1_u<<<2 * 1024, 512, 0, stream>>>(xb, w1t, ws1t, b1, bs1, cnt, slot_row,
                                        hbuf, 8, 0);
  gemm2_u<<<2 * 256, 512, 0, stream>>>(hbuf, w2t, ws2t, b2, bs2, cnt, slot_w,
                                       slot_dst, Y, 8, 0);
  final_k<<<8192, 256, 0, stream>>>(Y, out);
}